// Round 1
// baseline (3961.092 us; speedup 1.0000x reference)
//
#include <hip/hip_runtime.h>

// Problem dims (fixed by the reference)
#define Bdim 4096
#define Sdim 64
#define Hdim 128

// ---------- bf16 helpers (manual, version-proof) ----------
__device__ __forceinline__ unsigned short f2bf(float f) {
  unsigned int u = __float_as_uint(f);
  u = u + 0x7fffu + ((u >> 16) & 1u);   // RNE; inputs are finite
  return (unsigned short)(u >> 16);
}
__device__ __forceinline__ float bflo(unsigned int u) { return __uint_as_float(u << 16); }
__device__ __forceinline__ float bfhi(unsigned int u) { return __uint_as_float(u & 0xffff0000u); }
__device__ __forceinline__ float bf2f(unsigned short s) { return __uint_as_float(((unsigned int)s) << 16); }

__device__ __forceinline__ float sigm(float x) { return 1.0f / (1.0f + __expf(-x)); }
__device__ __forceinline__ float fast_tanh(float x) {
  float t = __expf(-2.0f * fabsf(x));
  float y = (1.0f - t) / (1.0f + t);
  return copysignf(y, x);
}

// ---------- cooperative loaders (256 threads) ----------
// 128x128 fp32 weight -> bf16 LDS, row-major [o][h]
__device__ __forceinline__ void load_w128(unsigned short* Ws, const float* __restrict__ W, int t) {
#pragma unroll
  for (int k = 0; k < 16; ++k) {
    int f = t + k * 256;               // 4096 float4s
    int o = f >> 5, c4 = f & 31;
    float4 v = *(const float4*)(W + o * 128 + c4 * 4);
    ushort4 p; p.x = f2bf(v.x); p.y = f2bf(v.y); p.z = f2bf(v.z); p.w = f2bf(v.w);
    *(ushort4*)(Ws + o * 128 + c4 * 4) = p;
  }
}

// 64 rows of X (fixed s) -> bf16 LDS [r][h]
__device__ __forceinline__ void load_x64(unsigned short* Xs, const float* __restrict__ X,
                                         int m0, int s, int t) {
#pragma unroll
  for (int k = 0; k < 8; ++k) {
    int f = t + k * 256;               // 2048 float4s
    int r = f >> 5, c4 = f & 31;
    float4 v = *(const float4*)(X + ((size_t)(m0 + r) * Sdim + s) * Hdim + c4 * 4);
    ushort4 p; p.x = f2bf(v.x); p.y = f2bf(v.y); p.z = f2bf(v.z); p.w = f2bf(v.w);
    *(ushort4*)(Xs + r * 128 + c4 * 4) = p;
  }
}

// ---------- 64x128 tile GEMM: acc[r][c] = sum_h Xs[r][h]*Ws[c][h] ----------
// thread (ty=t>>5, tx=t&31) owns rows ty*8+i (i<8), cols tx*4+j (j<4)
__device__ __forceinline__ void gemm64(float acc[8][4], const unsigned short* Xs,
                                       const unsigned short* Ws, int ty, int tx) {
#pragma unroll
  for (int i = 0; i < 8; ++i)
#pragma unroll
    for (int j = 0; j < 4; ++j) acc[i][j] = 0.0f;
#pragma unroll 4
  for (int h = 0; h < 128; h += 4) {
    float wv[4][4];
#pragma unroll
    for (int j = 0; j < 4; ++j) {
      uint2 w = *(const uint2*)(Ws + (tx * 4 + j) * 128 + h);
      wv[j][0] = bflo(w.x); wv[j][1] = bfhi(w.x);
      wv[j][2] = bflo(w.y); wv[j][3] = bfhi(w.y);
    }
#pragma unroll
    for (int i = 0; i < 8; ++i) {
      uint2 x = *(const uint2*)(Xs + (ty * 8 + i) * 128 + h);
      float x0 = bflo(x.x), x1 = bfhi(x.x), x2 = bflo(x.y), x3 = bfhi(x.y);
#pragma unroll
      for (int j = 0; j < 4; ++j)
        acc[i][j] += x0 * wv[j][0] + x1 * wv[j][1] + x2 * wv[j][2] + x3 * wv[j][3];
    }
  }
}

// ---------- kernel A: sumS[b,:] = sum_s (X[b,s,:] @ W1[s]^T) + sum_s b1[s,:] ----------
// grid 512 blocks x 8 rows; LDS 34 KB -> >=2 blocks/CU
__global__ __launch_bounds__(256) void sum_kernel(const float* __restrict__ X,
                                                  const float* __restrict__ W1,
                                                  const float* __restrict__ b1,
                                                  float* __restrict__ sumS) {
  __shared__ unsigned short Xs[8 * 128];
  __shared__ unsigned short Ws[128 * 128];
  const int t = threadIdx.x, ty = t >> 5, tx = t & 31;
  const int m0 = blockIdx.x * 8;
  float acc[4] = {0.f, 0.f, 0.f, 0.f};
  for (int s = 0; s < 64; ++s) {
    {  // 8x128 X tile: exactly 256 float4s
      int r = t >> 5, c4 = t & 31;
      float4 v = *(const float4*)(X + ((size_t)(m0 + r) * Sdim + s) * Hdim + c4 * 4);
      ushort4 p; p.x = f2bf(v.x); p.y = f2bf(v.y); p.z = f2bf(v.z); p.w = f2bf(v.w);
      *(ushort4*)(Xs + r * 128 + c4 * 4) = p;
    }
    load_w128(Ws, W1 + (size_t)s * 16384, t);
    __syncthreads();
#pragma unroll 4
    for (int h = 0; h < 128; h += 4) {
      uint2 xw = *(const uint2*)(Xs + ty * 128 + h);
      float x0 = bflo(xw.x), x1 = bfhi(xw.x), x2 = bflo(xw.y), x3 = bfhi(xw.y);
#pragma unroll
      for (int j = 0; j < 4; ++j) {
        uint2 w = *(const uint2*)(Ws + (tx * 4 + j) * 128 + h);
        acc[j] += x0 * bflo(w.x) + x1 * bfhi(w.x) + x2 * bflo(w.y) + x3 * bfhi(w.y);
      }
    }
    __syncthreads();
  }
  // + sum_s b1  (tiny, fully cached)
  float4 bs = make_float4(0.f, 0.f, 0.f, 0.f);
  for (int s = 0; s < 64; ++s) {
    float4 bv = *(const float4*)(b1 + s * 128 + tx * 4);
    bs.x += bv.x; bs.y += bv.y; bs.z += bv.z; bs.w += bv.w;
  }
  float4 o = make_float4(acc[0] + bs.x, acc[1] + bs.y, acc[2] + bs.z, acc[3] + bs.w);
  *(float4*)(sumS + (size_t)(m0 + ty) * 128 + tx * 4) = o;
}

// ---------- kernel B: fully fused per (s, 64-row tile) ----------
// recompute state1 -> state2 = sumS - state1 -> state3 -> GRU -> out = X + h_new
// LDS exactly 64 KiB -> 2 blocks/CU
__global__ __launch_bounds__(256) void fused_kernel(
    const float* __restrict__ X, const float* __restrict__ W1, const float* __restrict__ b1,
    const float* __restrict__ W3, const float* __restrict__ b3,
    const float* __restrict__ Wih, const float* __restrict__ bih,
    const float* __restrict__ Whh, const float* __restrict__ bhh,
    const float* __restrict__ sumS, float* __restrict__ out) {
  __shared__ unsigned short Xs[64 * 128];   // 16 KB, lives whole kernel (X tile)
  __shared__ unsigned short Ws[128 * 128];  // 32 KB, rotated through 8 weights
  __shared__ unsigned short S2[64 * 128];   // 16 KB, state2 then state3
  const int t = threadIdx.x, ty = t >> 5, tx = t & 31;
  const int s = blockIdx.x;
  const int m0 = blockIdx.y * 64;
  float accA[8][4], accB[8][4];

  load_x64(Xs, X, m0, s, t);
  load_w128(Ws, W1 + (size_t)s * 16384, t);
  __syncthreads();

  // state1 = X@W1[s]^T (+b1), state2 = sumS - state1 -> S2
  gemm64(accA, Xs, Ws, ty, tx);
  {
    float4 b1v = *(const float4*)(b1 + s * 128 + tx * 4);
#pragma unroll
    for (int i = 0; i < 8; ++i) {
      float4 sv = *(const float4*)(sumS + (size_t)(m0 + ty * 8 + i) * 128 + tx * 4);
      ushort4 p;
      p.x = f2bf(sv.x - (accA[i][0] + b1v.x));
      p.y = f2bf(sv.y - (accA[i][1] + b1v.y));
      p.z = f2bf(sv.z - (accA[i][2] + b1v.z));
      p.w = f2bf(sv.w - (accA[i][3] + b1v.w));
      *(ushort4*)(S2 + (ty * 8 + i) * 128 + tx * 4) = p;
    }
  }
  __syncthreads();                       // W1 reads done; state2 visible
  load_w128(Ws, W3 + (size_t)s * 16384, t);
  __syncthreads();
  gemm64(accA, S2, Ws, ty, tx);          // state3 pre-bias
  __syncthreads();                       // all state2 reads done
  {
    float4 b3v = *(const float4*)(b3 + s * 128 + tx * 4);
#pragma unroll
    for (int i = 0; i < 8; ++i) {
      ushort4 p;
      p.x = f2bf(accA[i][0] + b3v.x);
      p.y = f2bf(accA[i][1] + b3v.y);
      p.z = f2bf(accA[i][2] + b3v.z);
      p.w = f2bf(accA[i][3] + b3v.w);
      *(ushort4*)(S2 + (ty * 8 + i) * 128 + tx * 4) = p;   // S2 := state3
    }
  }

  float rr[8][4], zz[8][4];
#pragma unroll 1
  for (int g = 0; g < 3; ++g) {          // gates r, z, n
    load_w128(Ws, Wih + (size_t)g * 16384, t);   // Ws last read before prev barrier
    __syncthreads();                     // Wih ready AND state3 visible
    gemm64(accA, S2, Ws, ty, tx);        // gi_g = state3 @ Wih_g^T
    __syncthreads();                     // Wih reads done
    load_w128(Ws, Whh + (size_t)g * 16384, t);
    __syncthreads();
    gemm64(accB, Xs, Ws, ty, tx);        // gh_g = X @ Whh_g^T
    float4 biv = *(const float4*)(bih + g * 128 + tx * 4);
    float4 bhv = *(const float4*)(bhh + g * 128 + tx * 4);
    float bi[4] = {biv.x, biv.y, biv.z, biv.w};
    float bh[4] = {bhv.x, bhv.y, bhv.z, bhv.w};
    if (g == 0) {
#pragma unroll
      for (int i = 0; i < 8; ++i)
#pragma unroll
        for (int j = 0; j < 4; ++j)
          rr[i][j] = sigm(accA[i][j] + bi[j] + accB[i][j] + bh[j]);
    } else if (g == 1) {
#pragma unroll
      for (int i = 0; i < 8; ++i)
#pragma unroll
        for (int j = 0; j < 4; ++j)
          zz[i][j] = sigm(accA[i][j] + bi[j] + accB[i][j] + bh[j]);
    } else {
#pragma unroll
      for (int i = 0; i < 8; ++i) {
        float o4[4];
#pragma unroll
        for (int j = 0; j < 4; ++j) {
          float gin = accA[i][j] + bi[j];
          float ghn = accB[i][j] + bh[j];
          float n = fast_tanh(gin + rr[i][j] * ghn);
          float xv = bf2f(Xs[(ty * 8 + i) * 128 + tx * 4 + j]);
          float hn = (1.0f - zz[i][j]) * n + zz[i][j] * xv;  // h = X
          o4[j] = xv + hn;
        }
        float4 ov = make_float4(o4[0], o4[1], o4[2], o4[3]);
        *(float4*)(out + ((size_t)(m0 + ty * 8 + i) * Sdim + s) * Hdim + tx * 4) = ov;
      }
    }
    __syncthreads();                     // Whh reads done before next gate's load
  }
}

extern "C" void kernel_launch(void* const* d_in, const int* in_sizes, int n_in,
                              void* d_out, int out_size, void* d_ws, size_t ws_size,
                              hipStream_t stream) {
  const float* X   = (const float*)d_in[0];
  const float* W1  = (const float*)d_in[1];
  const float* b1  = (const float*)d_in[2];
  const float* W3  = (const float*)d_in[3];
  const float* b3  = (const float*)d_in[4];
  const float* Wih = (const float*)d_in[5];
  const float* bih = (const float*)d_in[6];
  const float* Whh = (const float*)d_in[7];
  const float* bhh = (const float*)d_in[8];
  float* out  = (float*)d_out;
  float* sumS = (float*)d_ws;            // needs 4096*128*4 = 2 MiB of workspace

  sum_kernel<<<dim3(Bdim / 8), 256, 0, stream>>>(X, W1, b1, sumS);
  fused_kernel<<<dim3(Sdim, Bdim / 64), 256, 0, stream>>>(X, W1, b1, W3, b3,
                                                          Wih, bih, Whh, bhh, sumS, out);
}

// Round 2
// 627.703 us; speedup vs baseline: 6.3105x; 6.3105x over previous
//
#include <hip/hip_runtime.h>
#include <stdint.h>

#define Bdim 4096
#define Sdim 64
#define Hdim 128

typedef __attribute__((ext_vector_type(8))) __bf16 bf16x8;
typedef __attribute__((ext_vector_type(4))) float f32x4;
typedef __attribute__((ext_vector_type(8))) unsigned short ushort8v;

// ---------- helpers ----------
__device__ __forceinline__ unsigned short f2bf(float f) {
  unsigned int u = __float_as_uint(f);
  u = u + 0x7fffu + ((u >> 16) & 1u);   // RNE; inputs finite
  return (unsigned short)(u >> 16);
}
__device__ __forceinline__ float bf2f(unsigned short s) {
  return __uint_as_float(((unsigned int)s) << 16);
}
__device__ __forceinline__ float sigm(float x) { return 1.0f / (1.0f + __expf(-x)); }
__device__ __forceinline__ float fast_tanh(float x) {
  float t = __expf(-2.0f * fabsf(x));
  float y = (1.0f - t) / (1.0f + t);
  return copysignf(y, x);
}

// async global->LDS, 16 B per lane. lds dst = wave-uniform base (+ lane*16 by HW).
__device__ __forceinline__ void glds16(const void* g, void* l) {
  auto* gp = reinterpret_cast<__attribute__((address_space(1))) unsigned int*>(
      reinterpret_cast<uintptr_t>(g));
  auto* lp = reinterpret_cast<__attribute__((address_space(3))) unsigned int*>(
      static_cast<uint32_t>(reinterpret_cast<uintptr_t>(l)));
  __builtin_amdgcn_global_load_lds(gp, lp, 16, 0, 0);
}

// stage one 128x128 bf16 weight (fragment-linear in ws) into LDS: 32 chunks of 1KB
__device__ __forceinline__ void stage_w(unsigned short* Ws, const unsigned short* wsrc,
                                        int w, int lane) {
#pragma unroll
  for (int i = 0; i < 8; ++i) {
    int chunk = w * 8 + i;
    glds16(wsrc + (size_t)chunk * 512 + lane * 8, Ws + chunk * 512);
  }
}

// stage 64x128 fp32 tile (row stride rsF floats) -> bf16 LDS, XOR-swizzled 16B blocks
__device__ __forceinline__ void stage_tile(unsigned short* L, const float* __restrict__ src,
                                           int rsF, int t) {
#pragma unroll
  for (int it = 0; it < 4; ++it) {
    int c = t + it * 256;            // 0..1023 chunks of 8 elements
    int r = c >> 4, bblk = c & 15;
    const float* p = src + (size_t)r * rsF + bblk * 8;
    float4 v0 = *(const float4*)p;
    float4 v1 = *(const float4*)(p + 4);
    int bp = bblk ^ (r & 15);
    ushort8v o;
    o[0] = f2bf(v0.x); o[1] = f2bf(v0.y); o[2] = f2bf(v0.z); o[3] = f2bf(v0.w);
    o[4] = f2bf(v1.x); o[5] = f2bf(v1.y); o[6] = f2bf(v1.z); o[7] = f2bf(v1.w);
    *(ushort8v*)(L + r * 128 + bp * 8) = o;
  }
}

// one 64x128 tile-GEMM: acc[nt][reg] over rows w*16+quad*4+reg, cols nt*16+l15
// A: swizzled LDS (Xs/S2), B: fragment-linear Ws. acc init = bias[n] (or 0).
__device__ __forceinline__ void mfma_gemm(f32x4 acc[8], const unsigned short* A,
                                          const unsigned short* Ws,
                                          const float* __restrict__ biasN,
                                          int w, int lane) {
  const int quad = lane >> 4, l15 = lane & 15;
  bf16x8 a[4];
#pragma unroll
  for (int k0 = 0; k0 < 4; ++k0)
    a[k0] = *(const bf16x8*)&A[(w * 16 + l15) * 128 + (((k0 << 2) | quad) ^ l15) * 8];
#pragma unroll
  for (int nt = 0; nt < 8; ++nt) {
    float b = biasN ? biasN[nt * 16 + l15] : 0.0f;
    f32x4 c = {b, b, b, b};
#pragma unroll
    for (int k0 = 0; k0 < 4; ++k0)
      c = __builtin_amdgcn_mfma_f32_16x16x32_bf16(
          a[k0], *(const bf16x8*)&Ws[((nt * 4 + k0) * 64 + lane) * 8], c, 0, 0, 0);
    acc[nt] = c;
  }
}

// ---------- kernel 1: convert weights fp32 -> bf16 fragment-linear layout ----------
// 134 mats x 2048 chunks of 8 elems. dst linear = cid*8. Also b1s[h] = sum_s b1[s][h].
__global__ __launch_bounds__(256) void convert_kernel(
    const float* __restrict__ W1, const float* __restrict__ W3,
    const float* __restrict__ Wih, const float* __restrict__ Whh,
    const float* __restrict__ b1, unsigned short* __restrict__ wsW,
    float* __restrict__ b1s) {
  int cid = blockIdx.x * 256 + threadIdx.x;     // 0..274431
  int mat = cid >> 11;
  int within = cid & 2047;
  int f = within >> 6, lane = within & 63;
  int nt = f >> 2, k0 = f & 3;
  int o = nt * 16 + (lane & 15);
  int hb = k0 * 32 + (lane >> 4) * 8;
  const float* src;
  if (mat < 64)       src = W1 + (size_t)mat * 16384;
  else if (mat < 128) src = W3 + (size_t)(mat - 64) * 16384;
  else if (mat < 131) src = Wih + (size_t)(mat - 128) * 16384;
  else                src = Whh + (size_t)(mat - 131) * 16384;
  const float* p = src + o * 128 + hb;
  float4 v0 = *(const float4*)p;
  float4 v1 = *(const float4*)(p + 4);
  ushort8v oo;
  oo[0] = f2bf(v0.x); oo[1] = f2bf(v0.y); oo[2] = f2bf(v0.z); oo[3] = f2bf(v0.w);
  oo[4] = f2bf(v1.x); oo[5] = f2bf(v1.y); oo[6] = f2bf(v1.z); oo[7] = f2bf(v1.w);
  *(ushort8v*)(wsW + (size_t)cid * 8) = oo;
  if (cid < 128) {
    float a = 0.0f;
    for (int s = 0; s < 64; ++s) a += b1[s * 128 + cid];
    b1s[cid] = a;
  }
}

// ---------- kernel 2: partial sums over s-chunks ----------
// block (mtile bx, chunk by): acc += X(:,s)·W1[s]^T for s in chunk; -> sumP[by]
__global__ __launch_bounds__(256) void sum_kernel(
    const float* __restrict__ X, const unsigned short* __restrict__ wsW1,
    float* __restrict__ sumP) {
  __shared__ unsigned short Xs[64 * 128];
  __shared__ unsigned short Ws[128 * 128];
  const int t = threadIdx.x;
  const int lane = t & 63, w = t >> 6, quad = lane >> 4, l15 = lane & 15;
  const int m0 = blockIdx.x * 64;
  const int sc = blockIdx.y;
  f32x4 acc[8] = {};
  for (int si = 0; si < 8; ++si) {
    int s = sc * 8 + si;
    __syncthreads();   // prior iter's Xs/Ws reads complete
    stage_w(Ws, wsW1 + (size_t)s * 16384, w, lane);
    stage_tile(Xs, X + (size_t)m0 * 8192 + s * 128, 8192, t);
    __syncthreads();
    bf16x8 a[4];
#pragma unroll
    for (int k0 = 0; k0 < 4; ++k0)
      a[k0] = *(const bf16x8*)&Xs[(w * 16 + l15) * 128 + (((k0 << 2) | quad) ^ l15) * 8];
#pragma unroll
    for (int nt = 0; nt < 8; ++nt)
#pragma unroll
      for (int k0 = 0; k0 < 4; ++k0)
        acc[nt] = __builtin_amdgcn_mfma_f32_16x16x32_bf16(
            a[k0], *(const bf16x8*)&Ws[((nt * 4 + k0) * 64 + lane) * 8], acc[nt], 0, 0, 0);
  }
  float* dst = sumP + (size_t)sc * 524288 + (size_t)(m0 + w * 16) * 128;
#pragma unroll
  for (int nt = 0; nt < 8; ++nt)
#pragma unroll
    for (int r = 0; r < 4; ++r)
      dst[(quad * 4 + r) * 128 + nt * 16 + l15] = acc[nt][r];
}

// ---------- kernel 3: sumS = sum_c sumP[c] + b1s ----------
__global__ __launch_bounds__(256) void reduce_kernel(
    const float* __restrict__ sumP, const float* __restrict__ b1s,
    float* __restrict__ sumS) {
  int i = blockIdx.x * 256 + threadIdx.x;       // float4 index, 131072 total
  float4 acc = *(const float4*)(b1s + (i & 31) * 4);
#pragma unroll
  for (int c = 0; c < 8; ++c) {
    float4 v = *(const float4*)(sumP + (size_t)c * 524288 + (size_t)i * 4);
    acc.x += v.x; acc.y += v.y; acc.z += v.z; acc.w += v.w;
  }
  *(float4*)(sumS + (size_t)i * 4) = acc;
}

// ---------- kernel 4: fused state1..GRU..residual, one (64-row tile, s) per block ----------
__global__ __launch_bounds__(256) void fused_kernel(
    const float* __restrict__ X, const unsigned short* __restrict__ wsW,
    const float* __restrict__ b1, const float* __restrict__ b3,
    const float* __restrict__ bih, const float* __restrict__ bhh,
    const float* __restrict__ sumS, float* __restrict__ out) {
  __shared__ unsigned short Xs[64 * 128];   // 16 KB, swizzled, lives whole kernel
  __shared__ unsigned short S2[64 * 128];   // 16 KB, swizzled, state2 then state3
  __shared__ unsigned short Ws[128 * 128];  // 32 KB, fragment-linear, rotated x8
  const int t = threadIdx.x;
  const int lane = t & 63, w = t >> 6, quad = lane >> 4, l15 = lane & 15;
  const int m0 = blockIdx.x * 64;
  const int s = blockIdx.y;
  const unsigned short* W1s = wsW + (size_t)s * 16384;
  const unsigned short* W3s = wsW + (size_t)(64 + s) * 16384;
  const unsigned short* Wihs = wsW + (size_t)128 * 16384;
  const unsigned short* Whhs = wsW + (size_t)131 * 16384;

  stage_w(Ws, W1s, w, lane);
  stage_tile(Xs, X + (size_t)m0 * 8192 + s * 128, 8192, t);
  __syncthreads();

  f32x4 gi[8], gh[8];
  // GEMM1: state1 = X·W1^T + b1; state2 = sumS - state1 -> S2
  mfma_gemm(gi, Xs, Ws, b1 + s * 128, w, lane);
  {
    const float* sp = sumS + (size_t)(m0 + w * 16) * 128;
#pragma unroll
    for (int nt = 0; nt < 8; ++nt) {
      int n = nt * 16 + l15;
#pragma unroll
      for (int r = 0; r < 4; ++r) {
        int rr = quad * 4 + r;      // row within wave strip; S2 rows are wave-private
        float v = sp[rr * 128 + n] - gi[nt][r];
        S2[(w * 16 + rr) * 128 + ((n >> 3) ^ rr) * 8 + (n & 7)] = f2bf(v);
      }
    }
  }
  __syncthreads();                  // W1 reads done everywhere
  stage_w(Ws, W3s, w, lane);
  __syncthreads();
  // GEMM2: state3 = state2·W3^T + b3 -> S2 (in place; rows wave-private, reads precede writes)
  mfma_gemm(gi, S2, Ws, b3 + s * 128, w, lane);
#pragma unroll
  for (int nt = 0; nt < 8; ++nt) {
    int n = nt * 16 + l15;
#pragma unroll
    for (int r = 0; r < 4; ++r) {
      int rr = quad * 4 + r;
      S2[(w * 16 + rr) * 128 + ((n >> 3) ^ rr) * 8 + (n & 7)] = f2bf(gi[nt][r]);
    }
  }

  float rg[8][4], zg[8][4];
#pragma unroll
  for (int g = 0; g < 3; ++g) {     // gates r, z, n
    __syncthreads();                // prior Ws reads done
    stage_w(Ws, Wihs + (size_t)g * 16384, w, lane);
    __syncthreads();
    mfma_gemm(gi, S2, Ws, bih + g * 128, w, lane);   // gi_g = state3·Wih_g^T + bih_g
    __syncthreads();
    stage_w(Ws, Whhs + (size_t)g * 16384, w, lane);
    __syncthreads();
    mfma_gemm(gh, Xs, Ws, bhh + g * 128, w, lane);   // gh_g = X·Whh_g^T + bhh_g
    if (g == 0) {
#pragma unroll
      for (int nt = 0; nt < 8; ++nt)
#pragma unroll
        for (int r = 0; r < 4; ++r) rg[nt][r] = sigm(gi[nt][r] + gh[nt][r]);
    } else if (g == 1) {
#pragma unroll
      for (int nt = 0; nt < 8; ++nt)
#pragma unroll
        for (int r = 0; r < 4; ++r) zg[nt][r] = sigm(gi[nt][r] + gh[nt][r]);
    } else {
      float* op = out + ((size_t)(m0 + w * 16) * 64 + s) * 128;
#pragma unroll
      for (int nt = 0; nt < 8; ++nt) {
        int n = nt * 16 + l15;
#pragma unroll
        for (int r = 0; r < 4; ++r) {
          int rr = quad * 4 + r;
          float nv = fast_tanh(gi[nt][r] + rg[nt][r] * gh[nt][r]);
          float xv = bf2f(Xs[(w * 16 + rr) * 128 + ((n >> 3) ^ rr) * 8 + (n & 7)]);
          float hn = (1.0f - zg[nt][r]) * nv + zg[nt][r] * xv;   // h_prev = X
          op[(size_t)rr * 8192 + n] = xv + hn;                    // out = X + h_new
        }
      }
    }
  }
}

extern "C" void kernel_launch(void* const* d_in, const int* in_sizes, int n_in,
                              void* d_out, int out_size, void* d_ws, size_t ws_size,
                              hipStream_t stream) {
  const float* X   = (const float*)d_in[0];
  const float* W1  = (const float*)d_in[1];
  const float* b1  = (const float*)d_in[2];
  const float* W3  = (const float*)d_in[3];
  const float* b3  = (const float*)d_in[4];
  const float* Wih = (const float*)d_in[5];
  const float* bih = (const float*)d_in[6];
  const float* Whh = (const float*)d_in[7];
  const float* bhh = (const float*)d_in[8];
  float* out = (float*)d_out;

  // ws layout: [weights bf16 134*32KB][b1s 512B][sumS 2MB][sumP 16MB] ~= 22.2 MiB
  const size_t W_BYTES = (size_t)134 * 32768;
  unsigned short* wsW = (unsigned short*)d_ws;
  float* b1s  = (float*)((char*)d_ws + W_BYTES);
  float* sumS = (float*)((char*)d_ws + W_BYTES + 512);
  float* sumP = (float*)((char*)d_ws + W_BYTES + 512 + 2097152);

  convert_kernel<<<1072, 256, 0, stream>>>(W1, W3, Wih, Whh, b1, wsW, b1s);
  sum_kernel<<<dim3(64, 8), 256, 0, stream>>>(X, wsW, sumP);
  reduce_kernel<<<512, 256, 0, stream>>>(sumP, b1s, sumS);
  fused_kernel<<<dim3(64, 64), 256, 0, stream>>>(X, wsW, b1, b3, bih, bhh, sumS, out);
}

// Round 3
// 446.111 us; speedup vs baseline: 8.8792x; 1.4071x over previous
//
#include <hip/hip_runtime.h>
#include <stdint.h>

#define Bdim 4096
#define Sdim 64
#define Hdim 128

typedef __attribute__((ext_vector_type(8))) __bf16 bf16x8;
typedef __attribute__((ext_vector_type(4))) float f32x4;
typedef __attribute__((ext_vector_type(8))) unsigned short ushort8v;

// ---------- helpers ----------
__device__ __forceinline__ unsigned short f2bf(float f) {
  unsigned int u = __float_as_uint(f);
  u = u + 0x7fffu + ((u >> 16) & 1u);   // RNE; inputs finite
  return (unsigned short)(u >> 16);
}
__device__ __forceinline__ float bf2f(unsigned short s) {
  return __uint_as_float(((unsigned int)s) << 16);
}
__device__ __forceinline__ float sigm(float x) { return 1.0f / (1.0f + __expf(-x)); }
__device__ __forceinline__ float fast_tanh(float x) {
  float t = __expf(-2.0f * fabsf(x));
  float y = (1.0f - t) / (1.0f + t);
  return copysignf(y, x);
}

// async global->LDS, 16 B per lane (wave-uniform LDS base + lane*16 by HW)
__device__ __forceinline__ void glds16(const void* g, void* l) {
  auto* gp = reinterpret_cast<__attribute__((address_space(1))) unsigned int*>(
      reinterpret_cast<uintptr_t>(g));
  auto* lp = reinterpret_cast<__attribute__((address_space(3))) unsigned int*>(
      static_cast<uint32_t>(reinterpret_cast<uintptr_t>(l)));
  __builtin_amdgcn_global_load_lds(gp, lp, 16, 0, 0);
}

// stage one 128x128 bf16 weight (fragment-linear) into LDS; 512 threads = 8 waves x 4 KB
__device__ __forceinline__ void stage_w(unsigned short* Ws, const unsigned short* wsrc,
                                        int w, int lane) {
#pragma unroll
  for (int i = 0; i < 4; ++i) {
    int chunk = w * 4 + i;             // 32 chunks of 1 KB
    glds16(wsrc + (size_t)chunk * 512 + lane * 8, Ws + chunk * 512);
  }
}

// stage 128x128 fp32 tile (row stride rsF floats) -> bf16 LDS, XOR-swizzled 16B blocks
__device__ __forceinline__ void stage_tile512(unsigned short* L, const float* __restrict__ src,
                                              int rsF, int t) {
#pragma unroll
  for (int it = 0; it < 4; ++it) {
    int c = t + it * 512;              // 2048 chunks of 8 elems
    int r = c >> 4, bblk = c & 15;
    const float* p = src + (size_t)r * rsF + bblk * 8;
    float4 v0 = *(const float4*)p;
    float4 v1 = *(const float4*)(p + 4);
    ushort8v o;
    o[0] = f2bf(v0.x); o[1] = f2bf(v0.y); o[2] = f2bf(v0.z); o[3] = f2bf(v0.w);
    o[4] = f2bf(v1.x); o[5] = f2bf(v1.y); o[6] = f2bf(v1.z); o[7] = f2bf(v1.w);
    *(ushort8v*)(L + r * 128 + (bblk ^ (r & 15)) * 8) = o;
  }
}

// one 128x128-tile GEMM step (per wave: its 16-row strip x 128 cols)
// A: swizzled LDS, B: fragment-linear Ws; acc init = bias (or passthrough-accumulate below)
__device__ __forceinline__ void mfma_gemm(f32x4 acc[8], const unsigned short* A,
                                          const unsigned short* Ws,
                                          const float* __restrict__ biasN,
                                          int w, int lane) {
  const int quad = lane >> 4, l15 = lane & 15;
  bf16x8 a[4];
#pragma unroll
  for (int k0 = 0; k0 < 4; ++k0)
    a[k0] = *(const bf16x8*)&A[(w * 16 + l15) * 128 + (((k0 << 2) | quad) ^ l15) * 8];
#pragma unroll
  for (int nt = 0; nt < 8; ++nt) {
    float b = biasN ? biasN[nt * 16 + l15] : 0.0f;
    f32x4 c = {b, b, b, b};
#pragma unroll
    for (int k0 = 0; k0 < 4; ++k0)
      c = __builtin_amdgcn_mfma_f32_16x16x32_bf16(
          a[k0], *(const bf16x8*)&Ws[((nt * 4 + k0) * 64 + lane) * 8], c, 0, 0, 0);
    acc[nt] = c;
  }
}

// ---------- kernel 1: weights fp32 -> bf16 fragment-linear; b1s = sum_s b1 ----------
__global__ __launch_bounds__(256) void convert_kernel(
    const float* __restrict__ W1, const float* __restrict__ W3,
    const float* __restrict__ Wih, const float* __restrict__ Whh,
    const float* __restrict__ b1, unsigned short* __restrict__ wsW,
    float* __restrict__ b1s) {
  int cid = blockIdx.x * 256 + threadIdx.x;     // 0..274431
  int mat = cid >> 11;
  int within = cid & 2047;
  int f = within >> 6, lane = within & 63;
  int nt = f >> 2, k0 = f & 3;
  int o = nt * 16 + (lane & 15);
  int hb = k0 * 32 + (lane >> 4) * 8;
  const float* src;
  if (mat < 64)       src = W1 + (size_t)mat * 16384;
  else if (mat < 128) src = W3 + (size_t)(mat - 64) * 16384;
  else if (mat < 131) src = Wih + (size_t)(mat - 128) * 16384;
  else                src = Whh + (size_t)(mat - 131) * 16384;
  const float* p = src + o * 128 + hb;
  float4 v0 = *(const float4*)p;
  float4 v1 = *(const float4*)(p + 4);
  ushort8v oo;
  oo[0] = f2bf(v0.x); oo[1] = f2bf(v0.y); oo[2] = f2bf(v0.z); oo[3] = f2bf(v0.w);
  oo[4] = f2bf(v1.x); oo[5] = f2bf(v1.y); oo[6] = f2bf(v1.z); oo[7] = f2bf(v1.w);
  *(ushort8v*)(wsW + (size_t)cid * 8) = oo;
  if (cid < 128) {
    float a = 0.0f;
    for (int s = 0; s < 64; ++s) a += b1[s * 128 + cid];
    b1s[cid] = a;
  }
}

// ---------- kernel 2: partial sums, fully double-buffered pipeline ----------
// grid (32 m-tiles of 128, 8 s-chunks); 512 threads
__global__ __launch_bounds__(512) void sum_kernel(
    const float* __restrict__ X, const unsigned short* __restrict__ wsW1,
    float* __restrict__ sumP) {
  __shared__ unsigned short Xs[2][128 * 128];   // 64 KB
  __shared__ unsigned short Ws[2][128 * 128];   // 64 KB
  const int t = threadIdx.x;
  const int lane = t & 63, w = t >> 6, quad = lane >> 4, l15 = lane & 15;
  const int m0 = blockIdx.x * 128;
  const int sc = blockIdx.y;
  f32x4 acc[8] = {};

  // prologue: stage s-index 0 into buf0
  stage_w(Ws[0], wsW1 + (size_t)(sc * 8) * 16384, w, lane);
  stage_tile512(Xs[0], X + (size_t)m0 * 8192 + (sc * 8) * 128, 8192, t);
  __syncthreads();

  for (int si = 0; si < 8; ++si) {
    const int cur = si & 1;
    float4 xr[4][2];
    if (si < 7) {
      int s = sc * 8 + si + 1;
      stage_w(Ws[cur ^ 1], wsW1 + (size_t)s * 16384, w, lane);
#pragma unroll
      for (int it = 0; it < 4; ++it) {
        int c = t + it * 512;
        int r = c >> 4, bblk = c & 15;
        const float* p = X + (size_t)(m0 + r) * 8192 + s * 128 + bblk * 8;
        xr[it][0] = *(const float4*)p;
        xr[it][1] = *(const float4*)(p + 4);
      }
    }
    // GEMM accumulate on current buffers
    {
      bf16x8 a[4];
#pragma unroll
      for (int k0 = 0; k0 < 4; ++k0)
        a[k0] = *(const bf16x8*)&Xs[cur][(w * 16 + l15) * 128 + (((k0 << 2) | quad) ^ l15) * 8];
#pragma unroll
      for (int nt = 0; nt < 8; ++nt)
#pragma unroll
        for (int k0 = 0; k0 < 4; ++k0)
          acc[nt] = __builtin_amdgcn_mfma_f32_16x16x32_bf16(
              a[k0], *(const bf16x8*)&Ws[cur][((nt * 4 + k0) * 64 + lane) * 8], acc[nt], 0, 0, 0);
    }
    if (si < 7) {
#pragma unroll
      for (int it = 0; it < 4; ++it) {
        int c = t + it * 512;
        int r = c >> 4, bblk = c & 15;
        ushort8v o;
        o[0] = f2bf(xr[it][0].x); o[1] = f2bf(xr[it][0].y);
        o[2] = f2bf(xr[it][0].z); o[3] = f2bf(xr[it][0].w);
        o[4] = f2bf(xr[it][1].x); o[5] = f2bf(xr[it][1].y);
        o[6] = f2bf(xr[it][1].z); o[7] = f2bf(xr[it][1].w);
        *(ushort8v*)(Xs[cur ^ 1] + r * 128 + (bblk ^ (r & 15)) * 8) = o;
      }
    }
    __syncthreads();   // drains vmcnt (W ready) + lgkm (X converts visible); protects bufs
  }
  float* dst = sumP + (size_t)sc * 524288 + (size_t)(m0 + w * 16) * 128;
#pragma unroll
  for (int nt = 0; nt < 8; ++nt)
#pragma unroll
    for (int r = 0; r < 4; ++r)
      dst[(quad * 4 + r) * 128 + nt * 16 + l15] = acc[nt][r];
}

// ---------- kernel 3: sumS = sum_c sumP[c] + b1s ----------
__global__ __launch_bounds__(256) void reduce_kernel(
    const float* __restrict__ sumP, const float* __restrict__ b1s,
    float* __restrict__ sumS) {
  int i = blockIdx.x * 256 + threadIdx.x;       // float4 index, 131072 total
  float4 acc = *(const float4*)(b1s + (i & 31) * 4);
#pragma unroll
  for (int c = 0; c < 8; ++c) {
    float4 v = *(const float4*)(sumP + (size_t)c * 524288 + (size_t)i * 4);
    acc.x += v.x; acc.y += v.y; acc.z += v.z; acc.w += v.w;
  }
  *(float4*)(sumS + (size_t)i * 4) = acc;
}

// ---------- kernel 4: fused state1..GRU..residual ----------
// 512 threads, M-tile 128 x one s; weight LDS double-buffered; 8 barriers total.
// S2/Xs rows are wave-private (16-row strips) -> no barriers for state handoff.
__global__ __launch_bounds__(512) void fused_kernel(
    const float* __restrict__ X, const unsigned short* __restrict__ wsW,
    const float* __restrict__ b1, const float* __restrict__ b3,
    const float* __restrict__ bih, const float* __restrict__ bhh,
    const float* __restrict__ sumS, float* __restrict__ out) {
  __shared__ unsigned short Xs[128 * 128];      // 32 KB, lives whole kernel
  __shared__ unsigned short S2[128 * 128];      // 32 KB, state2 then state3
  __shared__ unsigned short Ws[2][128 * 128];   // 64 KB, double-buffered weights
  const int t = threadIdx.x;
  const int lane = t & 63, w = t >> 6, quad = lane >> 4, l15 = lane & 15;
  const int m0 = blockIdx.x * 128;
  const int s = blockIdx.y;

  const unsigned short* Wptr[8] = {
      wsW + (size_t)s * 16384,          // W1[s]
      wsW + (size_t)(64 + s) * 16384,   // W3[s]
      wsW + (size_t)128 * 16384,        // Wih r
      wsW + (size_t)131 * 16384,        // Whh r
      wsW + (size_t)129 * 16384,        // Wih z
      wsW + (size_t)132 * 16384,        // Whh z
      wsW + (size_t)130 * 16384,        // Wih n
      wsW + (size_t)133 * 16384};       // Whh n

  stage_w(Ws[0], Wptr[0], w, lane);
  stage_tile512(Xs, X + (size_t)m0 * 8192 + s * 128, 8192, t);
  __syncthreads();

  f32x4 gi[8], gh[8];
  float rg[8][4], zg[8][4];

  // ---- phase 0: state1 = X·W1^T + b1 ; state2 = sumS - state1 -> S2
  stage_w(Ws[1], Wptr[1], w, lane);
  mfma_gemm(gi, Xs, Ws[0], b1 + s * 128, w, lane);
  {
    const float* sp = sumS + (size_t)(m0 + w * 16) * 128;
#pragma unroll
    for (int nt = 0; nt < 8; ++nt) {
      int n = nt * 16 + l15;
#pragma unroll
      for (int r = 0; r < 4; ++r) {
        int rr = quad * 4 + r;
        float v = sp[rr * 128 + n] - gi[nt][r];
        S2[(w * 16 + rr) * 128 + ((n >> 3) ^ rr) * 8 + (n & 7)] = f2bf(v);
      }
    }
  }
  __syncthreads();
  // ---- phase 1: state3 = state2·W3^T + b3 -> S2 (in place, wave-private rows)
  stage_w(Ws[0], Wptr[2], w, lane);
  mfma_gemm(gi, S2, Ws[1], b3 + s * 128, w, lane);
#pragma unroll
  for (int nt = 0; nt < 8; ++nt) {
    int n = nt * 16 + l15;
#pragma unroll
    for (int r = 0; r < 4; ++r) {
      int rr = quad * 4 + r;
      S2[(w * 16 + rr) * 128 + ((n >> 3) ^ rr) * 8 + (n & 7)] = f2bf(gi[nt][r]);
    }
  }
  __syncthreads();
  // ---- phase 2: gi_r = state3·Wih_r^T + bih_r
  stage_w(Ws[1], Wptr[3], w, lane);
  mfma_gemm(gi, S2, Ws[0], bih + 0 * 128, w, lane);
  __syncthreads();
  // ---- phase 3: gh_r = X·Whh_r^T + bhh_r ; r-gate
  stage_w(Ws[0], Wptr[4], w, lane);
  mfma_gemm(gh, Xs, Ws[1], bhh + 0 * 128, w, lane);
#pragma unroll
  for (int nt = 0; nt < 8; ++nt)
#pragma unroll
    for (int r = 0; r < 4; ++r) rg[nt][r] = sigm(gi[nt][r] + gh[nt][r]);
  __syncthreads();
  // ---- phase 4: gi_z
  stage_w(Ws[1], Wptr[5], w, lane);
  mfma_gemm(gi, S2, Ws[0], bih + 1 * 128, w, lane);
  __syncthreads();
  // ---- phase 5: gh_z ; z-gate
  stage_w(Ws[0], Wptr[6], w, lane);
  mfma_gemm(gh, Xs, Ws[1], bhh + 1 * 128, w, lane);
#pragma unroll
  for (int nt = 0; nt < 8; ++nt)
#pragma unroll
    for (int r = 0; r < 4; ++r) zg[nt][r] = sigm(gi[nt][r] + gh[nt][r]);
  __syncthreads();
  // ---- phase 6: gi_n
  stage_w(Ws[1], Wptr[7], w, lane);
  mfma_gemm(gi, S2, Ws[0], bih + 2 * 128, w, lane);
  __syncthreads();
  // ---- phase 7: gh_n ; n-gate, blend, residual, store
  mfma_gemm(gh, Xs, Ws[1], bhh + 2 * 128, w, lane);
  {
    float* op = out + ((size_t)(m0 + w * 16) * 64 + s) * 128;
#pragma unroll
    for (int nt = 0; nt < 8; ++nt) {
      int n = nt * 16 + l15;
#pragma unroll
      for (int r = 0; r < 4; ++r) {
        int rr = quad * 4 + r;
        float nv = fast_tanh(gi[nt][r] + rg[nt][r] * gh[nt][r]);
        float xv = bf2f(Xs[(w * 16 + rr) * 128 + ((n >> 3) ^ rr) * 8 + (n & 7)]);
        float hn = (1.0f - zg[nt][r]) * nv + zg[nt][r] * xv;   // h_prev = X
        op[(size_t)rr * 8192 + n] = xv + hn;                    // out = X + h_new
      }
    }
  }
}

extern "C" void kernel_launch(void* const* d_in, const int* in_sizes, int n_in,
                              void* d_out, int out_size, void* d_ws, size_t ws_size,
                              hipStream_t stream) {
  const float* X   = (const float*)d_in[0];
  const float* W1  = (const float*)d_in[1];
  const float* b1  = (const float*)d_in[2];
  const float* W3  = (const float*)d_in[3];
  const float* b3  = (const float*)d_in[4];
  const float* Wih = (const float*)d_in[5];
  const float* bih = (const float*)d_in[6];
  const float* Whh = (const float*)d_in[7];
  const float* bhh = (const float*)d_in[8];
  float* out = (float*)d_out;

  // ws layout: [weights bf16 134*32KB][b1s 512B][sumS 2MB][sumP 16MB] ~= 22.2 MiB
  const size_t W_BYTES = (size_t)134 * 32768;
  unsigned short* wsW = (unsigned short*)d_ws;
  float* b1s  = (float*)((char*)d_ws + W_BYTES);
  float* sumS = (float*)((char*)d_ws + W_BYTES + 512);
  float* sumP = (float*)((char*)d_ws + W_BYTES + 512 + 2097152);

  convert_kernel<<<1072, 256, 0, stream>>>(W1, W3, Wih, Whh, b1, wsW, b1s);
  sum_kernel<<<dim3(32, 8), 512, 0, stream>>>(X, wsW, sumP);
  reduce_kernel<<<512, 256, 0, stream>>>(sumP, b1s, sumS);
  fused_kernel<<<dim3(32, 64), 512, 0, stream>>>(X, wsW, b1, b3, bih, bhh, sumS, out);
}